// Round 2
// baseline (645.219 us; speedup 1.0000x reference)
//
#include <hip/hip_runtime.h>
#include <hip/hip_bf16.h>
#include <stdint.h>

#define TT   512
#define BB   128
#define DIN  256
#define DH   512
#define DOUT 256
#define NV   (BB*DH)     // 65536 neurons (b,h)
#define NLOG (BB*DOUT)   // 32768 logits per t

// ---------------- GEMM1: CUR = Xc @ Win + bin, strict f32 -------------------
// Single accumulator per output element, fmaf chain over k ASCENDING —
// replicates BLAS sgemm microkernel accumulation so the f32 result tracks
// the numpy reference bitwise (or within ~1 ulp).
__global__ __launch_bounds__(256) void gemm1_f32(
    const float* __restrict__ X, const float* __restrict__ Win,
    const float* __restrict__ bin, float* __restrict__ CUR, int Mc)
{
    __shared__ float As[16][68];   // [k][m]
    __shared__ float Bs[16][68];   // [k][n]
    const int bm = blockIdx.x * 64;
    const int bn = blockIdx.y * 64;
    const int tid = threadIdx.x;
    const int tx = tid & 15, ty = tid >> 4;
    const int ma = tid >> 2, kq = tid & 3;    // A staging: 64 rows x 4 quads
    const int kb = tid >> 4, nq = tid & 15;   // B staging: 16 k x 16 n-quads
    float acc[4][4] = {};
    for (int k0 = 0; k0 < DIN; k0 += 16) {
        __syncthreads();
        float4 a4 = *reinterpret_cast<const float4*>(
            &X[(size_t)(bm + ma)*DIN + k0 + kq*4]);
        As[kq*4+0][ma] = a4.x;
        As[kq*4+1][ma] = a4.y;
        As[kq*4+2][ma] = a4.z;
        As[kq*4+3][ma] = a4.w;
        float4 b4 = *reinterpret_cast<const float4*>(
            &Win[(size_t)(k0 + kb)*DH + bn + nq*4]);
        Bs[kb][nq*4+0] = b4.x;
        Bs[kb][nq*4+1] = b4.y;
        Bs[kb][nq*4+2] = b4.z;
        Bs[kb][nq*4+3] = b4.w;
        __syncthreads();
        #pragma unroll
        for (int kk = 0; kk < 16; ++kk) {   // k strictly ascending
            float a[4], b[4];
            #pragma unroll
            for (int i = 0; i < 4; ++i) a[i] = As[kk][ty*4+i];
            #pragma unroll
            for (int j = 0; j < 4; ++j) b[j] = Bs[kk][tx*4+j];
            #pragma unroll
            for (int i = 0; i < 4; ++i)
                #pragma unroll
                for (int j = 0; j < 4; ++j)
                    acc[i][j] = fmaf(a[i], b[j], acc[i][j]);
        }
    }
    #pragma unroll
    for (int i = 0; i < 4; ++i) {
        const size_t row = (size_t)(bm + ty*4 + i)*DH + bn;
        #pragma unroll
        for (int j = 0; j < 4; ++j)
            CUR[row + tx*4 + j] = __fadd_rn(acc[i][j], bin[bn + tx*4 + j]);
    }
}

// ---------------- scan: per-(b,h) strict-f32 recurrence over Tc steps -------
// numpy op order: V' = ((0.9f*V) + cur) + s*w_rec − s*1.0f, each op f32 RN,
// no FMA contraction. spike = (V − 1 > 0) ⟺ V > 1.0f (exact in f32).
__global__ __launch_bounds__(256) void scan_k(
    const float* __restrict__ CUR, const float* __restrict__ wrec,
    float* __restrict__ V, float* __restrict__ SPK,
    unsigned int* __restrict__ cnt, int Tc)
{
    const int i = blockIdx.x*256 + threadIdx.x;   // 0..NV-1
    float v = V[i];
    const float w = wrec[i & (DH-1)];
    int c = 0;
    for (int t = 0; t < Tc; ++t) {
        const size_t off = (size_t)t*NV + i;
        const float cur = CUR[off];
        const bool s = v > 1.0f;
        SPK[off] = s ? 1.0f : 0.0f;
        c += (int)s;
        float t1 = __fmul_rn(0.9f, v);
        float t2 = __fadd_rn(t1, cur);
        float t3 = __fadd_rn(t2, s ? w : 0.0f);
        v = __fsub_rn(t3, s ? 1.0f : 0.0f);
    }
    V[i] = v;
    #pragma unroll
    for (int o = 32; o > 0; o >>= 1) c += __shfl_down(c, o, 64);
    if ((threadIdx.x & 63) == 0) atomicAdd(cnt, (unsigned int)c);
}

// ---------------- GEMM2: Y = SPK @ Whead + bhead (f32, no feedback) ---------
__global__ __launch_bounds__(256) void gemm2_f32(
    const float* __restrict__ S, const float* __restrict__ Wh,
    const float* __restrict__ bh, float* __restrict__ Y, int Mc)
{
    __shared__ float As[16][68];
    __shared__ float Bs[16][68];
    const int bm = blockIdx.x * 64;
    const int bn = blockIdx.y * 64;
    const int tid = threadIdx.x;
    const int tx = tid & 15, ty = tid >> 4;
    const int ma = tid >> 2, kq = tid & 3;
    const int kb = tid >> 4, nq = tid & 15;
    float acc[4][4] = {};
    for (int k0 = 0; k0 < DH; k0 += 16) {
        __syncthreads();
        float4 a4 = *reinterpret_cast<const float4*>(
            &S[(size_t)(bm + ma)*DH + k0 + kq*4]);
        As[kq*4+0][ma] = a4.x;
        As[kq*4+1][ma] = a4.y;
        As[kq*4+2][ma] = a4.z;
        As[kq*4+3][ma] = a4.w;
        float4 b4 = *reinterpret_cast<const float4*>(
            &Wh[(size_t)(k0 + kb)*DOUT + bn + nq*4]);
        Bs[kb][nq*4+0] = b4.x;
        Bs[kb][nq*4+1] = b4.y;
        Bs[kb][nq*4+2] = b4.z;
        Bs[kb][nq*4+3] = b4.w;
        __syncthreads();
        #pragma unroll
        for (int kk = 0; kk < 16; ++kk) {
            float a[4], b[4];
            #pragma unroll
            for (int i = 0; i < 4; ++i) a[i] = As[kk][ty*4+i];
            #pragma unroll
            for (int j = 0; j < 4; ++j) b[j] = Bs[kk][tx*4+j];
            #pragma unroll
            for (int i = 0; i < 4; ++i)
                #pragma unroll
                for (int j = 0; j < 4; ++j)
                    acc[i][j] = fmaf(a[i], b[j], acc[i][j]);
        }
    }
    #pragma unroll
    for (int i = 0; i < 4; ++i) {
        const size_t row = (size_t)(bm + ty*4 + i)*DOUT + bn;
        #pragma unroll
        for (int j = 0; j < 4; ++j)
            Y[row + tx*4 + j] = __fadd_rn(acc[i][j], bh[bn + tx*4 + j]);
    }
}

// ---------------- readout: mean over T of logits ----------------------------
__global__ __launch_bounds__(256) void readout_k(
    const float* __restrict__ L, float* __restrict__ R)
{
    const int j = blockIdx.x*256 + threadIdx.x;   // 0..NLOG-1
    double s = 0.0;
    for (int t = 0; t < TT; ++t) s += (double)L[(size_t)t*NLOG + j];
    R[j] = (float)(s / (double)TT);
}

__global__ void finalize_k(const unsigned int* __restrict__ cnt,
                           float* __restrict__ srate)
{
    if (blockIdx.x == 0 && threadIdx.x == 0)
        srate[0] = (float)((double)cnt[0] / ((double)TT * (double)NV));
}

// ---------------------------------------------------------------------------
extern "C" void kernel_launch(void* const* d_in, const int* in_sizes, int n_in,
                              void* d_out, int out_size, void* d_ws, size_t ws_size,
                              hipStream_t stream)
{
    const float* x     = (const float*)d_in[0];   // [512][128][256]
    const float* Win   = (const float*)d_in[1];   // [256][512]
    const float* bin   = (const float*)d_in[2];   // [512]
    const float* wrec  = (const float*)d_in[3];   // [512]
    const float* Whead = (const float*)d_in[4];   // [512][256]
    const float* bhead = (const float*)d_in[5];   // [256]

    float* out     = (float*)d_out;
    float* readout = out;                         // 32768
    float* logits  = out + NLOG;                  // 512*32768
    float* srate   = out + NLOG + (size_t)TT*NLOG;// 1

    // pick largest t-chunk that fits ws: CUR(Tc*NV*4) + SPK(Tc*NV*4) + V(NV*4) + cnt
    const int cands[7] = {512, 256, 128, 64, 32, 16, 8};
    int Tc = 8;
    for (int ci = 0; ci < 7; ++ci) {
        size_t need = (size_t)cands[ci]*NV*8 + (size_t)NV*4 + 256;
        if (need <= ws_size) { Tc = cands[ci]; break; }
    }

    char* w = (char*)d_ws;
    float*        CUR = (float*)w;
    float*        SPK = (float*)(w + (size_t)Tc*NV*4);
    float*        V   = (float*)(w + (size_t)Tc*NV*8);
    unsigned int* cnt = (unsigned int*)(V + NV);

    // zero V state and spike counter (contiguous)
    hipMemsetAsync(V, 0, (size_t)NV*4 + 64, stream);

    for (int t0 = 0; t0 < TT; t0 += Tc) {
        const int Mc = Tc * BB;
        dim3 g1(Mc/64, DH/64);
        gemm1_f32<<<g1, 256, 0, stream>>>(x + (size_t)t0*BB*DIN, Win, bin, CUR, Mc);
        scan_k<<<NV/256, 256, 0, stream>>>(CUR, wrec, V, SPK, cnt, Tc);
        dim3 g2(Mc/64, DOUT/64);
        gemm2_f32<<<g2, 256, 0, stream>>>(SPK, Whead, bhead,
                                          logits + (size_t)t0*NLOG, Mc);
    }
    readout_k<<<NLOG/256, 256, 0, stream>>>(logits, readout);
    finalize_k<<<1, 64, 0, stream>>>(cnt, srate);
}

// Round 3
// 319.849 us; speedup vs baseline: 2.0173x; 2.0173x over previous
//
#include <hip/hip_runtime.h>
#include <hip/hip_bf16.h>
#include <stdint.h>

#define TT   512
#define BB   128
#define DIN  256
#define DH   512
#define DOUT 256
#define NV   (BB*DH)     // 65536
#define NLOG (BB*DOUT)   // 32768
#define MTOT (TT*BB)     // 65536

typedef unsigned short u16;
typedef __attribute__((ext_vector_type(8))) short bf16x8;
typedef __attribute__((ext_vector_type(4))) float f32x4;

// ========== GEMM1: CUR = X @ Win + bin, strict f32 (bitwise-np) =============
// 128x256 tile, 256 threads, 8x16 per thread, BK=16.
// Per output element: single accumulator, fmaf over k ascending — must not
// change (numerics feedback through the spike threshold).
__global__ __launch_bounds__(256, 2) void gemm1_f32(
    const float* __restrict__ X, const float* __restrict__ Win,
    const float* __restrict__ bin, float* __restrict__ CUR)
{
    __shared__ __align__(16) float As[16][132];   // [k][m]
    __shared__ __align__(16) float Bs[16][260];   // [k][n]
    const int bm = blockIdx.x * 128;
    const int bn = blockIdx.y * 256;
    const int t  = threadIdx.x;
    const int tx = t & 15, ty = t >> 4;
    const int arow = t >> 1, ahf = t & 1;        // A staging
    const int bkb  = t >> 4, bc0 = t & 15;       // B staging
    float acc[8][16] = {};   // [rh*4+i][cq*4+j]

    for (int k0 = 0; k0 < DIN; k0 += 16) {
        __syncthreads();
        // stage A tile 128x16: thread loads 2 float4 along k, scatters to [k][m]
        #pragma unroll
        for (int p = 0; p < 2; ++p) {
            float4 a4 = *reinterpret_cast<const float4*>(
                &X[(size_t)(bm + arow)*DIN + k0 + ahf*8 + p*4]);
            As[ahf*8 + p*4 + 0][arow] = a4.x;
            As[ahf*8 + p*4 + 1][arow] = a4.y;
            As[ahf*8 + p*4 + 2][arow] = a4.z;
            As[ahf*8 + p*4 + 3][arow] = a4.w;
        }
        // stage B tile 16x256: 4 float4 per thread, b128 stores (conflict-free)
        #pragma unroll
        for (int q = 0; q < 4; ++q) {
            float4 b4 = *reinterpret_cast<const float4*>(
                &Win[(size_t)(k0 + bkb)*DH + bn + (bc0 + 16*q)*4]);
            *reinterpret_cast<float4*>(&Bs[bkb][(bc0 + 16*q)*4]) = b4;
        }
        __syncthreads();
        #pragma unroll 4
        for (int kk = 0; kk < 16; ++kk) {
            float a[8], b[16];
            float4 a0 = *reinterpret_cast<const float4*>(&As[kk][ty*4]);
            float4 a1 = *reinterpret_cast<const float4*>(&As[kk][64 + ty*4]);
            a[0]=a0.x; a[1]=a0.y; a[2]=a0.z; a[3]=a0.w;
            a[4]=a1.x; a[5]=a1.y; a[6]=a1.z; a[7]=a1.w;
            #pragma unroll
            for (int cq = 0; cq < 4; ++cq) {
                float4 bq = *reinterpret_cast<const float4*>(&Bs[kk][cq*64 + tx*4]);
                b[cq*4+0]=bq.x; b[cq*4+1]=bq.y; b[cq*4+2]=bq.z; b[cq*4+3]=bq.w;
            }
            #pragma unroll
            for (int i = 0; i < 8; ++i)
                #pragma unroll
                for (int j = 0; j < 16; ++j)
                    acc[i][j] = fmaf(a[i], b[j], acc[i][j]);
        }
    }
    // epilogue: + bin, float4 stores
    #pragma unroll
    for (int rh = 0; rh < 2; ++rh)
        #pragma unroll
        for (int i = 0; i < 4; ++i) {
            const int row = bm + rh*64 + ty*4 + i;
            #pragma unroll
            for (int cq = 0; cq < 4; ++cq) {
                const int col = bn + cq*64 + tx*4;
                float4 o;
                o.x = __fadd_rn(acc[rh*4+i][cq*4+0], bin[col+0]);
                o.y = __fadd_rn(acc[rh*4+i][cq*4+1], bin[col+1]);
                o.z = __fadd_rn(acc[rh*4+i][cq*4+2], bin[col+2]);
                o.w = __fadd_rn(acc[rh*4+i][cq*4+3], bin[col+3]);
                *reinterpret_cast<float4*>(&CUR[(size_t)row*DH + col]) = o;
            }
        }
}

// ========== scan: strict-f32 recurrence, 8-deep load pipeline ===============
__global__ __launch_bounds__(256) void scan_k(
    const float* __restrict__ CUR, const float* __restrict__ wrec,
    u16* __restrict__ SPK, unsigned int* __restrict__ cnt)
{
    const int i = blockIdx.x*256 + threadIdx.x;
    float v = 0.0f;                       // V0 = 0
    const float w = wrec[i & (DH-1)];
    int c = 0;
    float cur[8], nxt[8];
    #pragma unroll
    for (int u = 0; u < 8; ++u) cur[u] = CUR[(size_t)u*NV + i];
    for (int t0 = 0; t0 < TT; t0 += 8) {
        if (t0 + 8 < TT) {
            #pragma unroll
            for (int u = 0; u < 8; ++u) nxt[u] = CUR[(size_t)(t0+8+u)*NV + i];
        }
        u16 sp[8];
        #pragma unroll
        for (int u = 0; u < 8; ++u) {
            const bool s = v > 1.0f;      // (V-1>0) <=> V>1 exactly in f32
            sp[u] = s ? (u16)0x3F80 : (u16)0;   // bf16 1.0 / 0.0
            c += (int)s;
            float t1 = __fmul_rn(0.9f, v);
            float t2 = __fadd_rn(t1, cur[u]);
            float t3 = __fadd_rn(t2, s ? w : 0.0f);
            v = __fsub_rn(t3, s ? 1.0f : 0.0f);
        }
        #pragma unroll
        for (int u = 0; u < 8; ++u) SPK[(size_t)(t0+u)*NV + i] = sp[u];
        #pragma unroll
        for (int u = 0; u < 8; ++u) cur[u] = nxt[u];
    }
    #pragma unroll
    for (int o = 32; o > 0; o >>= 1) c += __shfl_down(c, o, 64);
    if ((threadIdx.x & 63) == 0) atomicAdd(cnt, (unsigned int)c);
}

// ========== W_head -> bf16 transposed [DOUT][DH] ============================
__global__ __launch_bounds__(256) void trsp_k(
    const float* __restrict__ Wh, u16* __restrict__ WhT)
{
    const int id = blockIdx.x*256 + threadIdx.x;   // DOUT*DH
    const int n = id >> 9, k = id & (DH-1);
    __hip_bfloat16 h = __float2bfloat16(Wh[(size_t)k*DOUT + n]);
    WhT[id] = *reinterpret_cast<u16*>(&h);
}

// ========== GEMM2: logits = SPK @ Whead + bhead, bf16 MFMA ==================
// 128x128 tile, 4 waves (2x2), wave tile 64x64, BK=32, 16x16x32 MFMA.
// LDS chunk XOR-swizzle: chunk c (8 bf16) of row r stored at c^(r&3).
__global__ __launch_bounds__(256, 2) void gemm2_mfma(
    const u16* __restrict__ SPK, const u16* __restrict__ WhT,
    const float* __restrict__ bh, float* __restrict__ Y)
{
    __shared__ __align__(16) u16 Ab[128*32];
    __shared__ __align__(16) u16 Bb[128*32];
    const int bm = blockIdx.x * 128;
    const int bn = blockIdx.y * 128;
    const int t = threadIdx.x;
    const int lane = t & 63, wid = t >> 6;
    const int wr = wid >> 1, wc = wid & 1;
    const int srow = t >> 1, shf = t & 1;
    f32x4 acc[4][4];
    #pragma unroll
    for (int m = 0; m < 4; ++m)
        #pragma unroll
        for (int n = 0; n < 4; ++n) acc[m][n] = (f32x4){0.f,0.f,0.f,0.f};

    for (int k0 = 0; k0 < DH; k0 += 32) {
        __syncthreads();
        #pragma unroll
        for (int q = 0; q < 2; ++q) {
            const int c = shf*2 + q;
            uint4 va = *reinterpret_cast<const uint4*>(
                &SPK[(size_t)(bm + srow)*DH + k0 + c*8]);
            *reinterpret_cast<uint4*>(&Ab[srow*32 + ((c ^ (srow&3))*8)]) = va;
            uint4 vb = *reinterpret_cast<const uint4*>(
                &WhT[(size_t)(bn + srow)*DH + k0 + c*8]);
            *reinterpret_cast<uint4*>(&Bb[srow*32 + ((c ^ (srow&3))*8)]) = vb;
        }
        __syncthreads();
        const int l15 = lane & 15, lc = lane >> 4;
        bf16x8 af[4], bfr[4];
        #pragma unroll
        for (int m = 0; m < 4; ++m) {
            const int r = wr*64 + m*16 + l15;
            af[m] = *reinterpret_cast<const bf16x8*>(&Ab[r*32 + ((lc ^ (r&3))*8)]);
        }
        #pragma unroll
        for (int n = 0; n < 4; ++n) {
            const int r = wc*64 + n*16 + l15;
            bfr[n] = *reinterpret_cast<const bf16x8*>(&Bb[r*32 + ((lc ^ (r&3))*8)]);
        }
        #pragma unroll
        for (int m = 0; m < 4; ++m)
            #pragma unroll
            for (int n = 0; n < 4; ++n)
                acc[m][n] = __builtin_amdgcn_mfma_f32_16x16x32_bf16(
                    af[m], bfr[n], acc[m][n], 0, 0, 0);
    }
    // epilogue: D col = lane&15, row = (lane>>4)*4 + r  (m89/m91 layout)
    #pragma unroll
    for (int m = 0; m < 4; ++m)
        #pragma unroll
        for (int n = 0; n < 4; ++n) {
            const int row0 = bm + wr*64 + m*16 + (lane >> 4)*4;
            const int col  = bn + wc*64 + n*16 + (lane & 15);
            const float bv = bh[col];
            #pragma unroll
            for (int r = 0; r < 4; ++r)
                Y[(size_t)(row0 + r)*DOUT + col] = acc[m][n][r] + bv;
        }
}

// ========== readout: mean over T (two-stage, deterministic) =================
__global__ __launch_bounds__(256) void readout1(
    const float* __restrict__ L, double* __restrict__ P)
{
    const int j = blockIdx.x*256 + threadIdx.x;
    const int p = blockIdx.y;
    double s = 0.0;
    for (int u = 0; u < 64; ++u)
        s += (double)L[(size_t)(p*64 + u)*NLOG + j];
    P[(size_t)p*NLOG + j] = s;
}
__global__ __launch_bounds__(256) void readout2(
    const double* __restrict__ P, float* __restrict__ R)
{
    const int j = blockIdx.x*256 + threadIdx.x;
    double s = 0.0;
    #pragma unroll
    for (int p = 0; p < 8; ++p) s += P[(size_t)p*NLOG + j];
    R[j] = (float)(s / (double)TT);
}

__global__ void finalize_k(const unsigned int* __restrict__ cnt,
                           float* __restrict__ srate)
{
    if (threadIdx.x == 0)
        srate[0] = (float)((double)cnt[0] / ((double)TT * (double)NV));
}

// ============================================================================
extern "C" void kernel_launch(void* const* d_in, const int* in_sizes, int n_in,
                              void* d_out, int out_size, void* d_ws, size_t ws_size,
                              hipStream_t stream)
{
    const float* x     = (const float*)d_in[0];   // [512][128][256]
    const float* Win   = (const float*)d_in[1];   // [256][512]
    const float* bin   = (const float*)d_in[2];   // [512]
    const float* wrec  = (const float*)d_in[3];   // [512]
    const float* Whead = (const float*)d_in[4];   // [512][256]
    const float* bhead = (const float*)d_in[5];   // [256]

    float* out     = (float*)d_out;
    float* readout = out;                           // 32768
    float* logits  = out + NLOG;                    // 512*32768
    float* srate   = out + NLOG + (size_t)TT*NLOG;  // 1

    char* w = (char*)d_ws;
    size_t off = 0;
    float* CUR = (float*)(w + off);  off += (size_t)TT*NV*4;      // 128 MB
    u16*   SPK = (u16*)  (w + off);  off += (size_t)TT*NV*2;      //  64 MB
    u16*   WhT = (u16*)  (w + off);  off += (size_t)DOUT*DH*2;    // 256 KB
    double* P  = (double*)(w + off); off += (size_t)8*NLOG*8;     //   2 MB
    unsigned int* cnt = (unsigned int*)(w + off);

    hipMemsetAsync(cnt, 0, 256, stream);
    trsp_k<<<DOUT*DH/256, 256, 0, stream>>>(Whead, WhT);
    gemm1_f32<<<dim3(MTOT/128, DH/256), 256, 0, stream>>>(x, Win, bin, CUR);
    scan_k<<<NV/256, 256, 0, stream>>>(CUR, wrec, SPK, cnt);
    gemm2_mfma<<<dim3(MTOT/128, DOUT/128), 256, 0, stream>>>(SPK, WhT, bhead, logits);
    readout1<<<dim3(NLOG/256, 8), 256, 0, stream>>>(logits, P);
    readout2<<<NLOG/256, 256, 0, stream>>>(P, readout);
    finalize_k<<<1, 64, 0, stream>>>(cnt, srate);
}